// Round 2
// baseline (884.949 us; speedup 1.0000x reference)
//
#include <hip/hip_runtime.h>
#include <stdint.h>

// ---------------- types & helpers ----------------
typedef __attribute__((ext_vector_type(8))) short short8;
typedef __attribute__((ext_vector_type(4))) short short4v;
typedef __attribute__((ext_vector_type(4))) float f32x4;

#define GLOAD16(gp, lp) __builtin_amdgcn_global_load_lds( \
    (__attribute__((address_space(1))) void*)(gp),        \
    (__attribute__((address_space(3))) void*)(lp), 16, 0, 0)

__device__ __forceinline__ unsigned short f2bf(float f) {
    union { float f; unsigned u; } v; v.f = f;
    unsigned u = v.u + 0x7fffu + ((v.u >> 16) & 1u);
    return (unsigned short)(u >> 16);
}
__device__ __forceinline__ float bf2f(short s) {
    union { unsigned u; float f; } v;
    v.u = ((unsigned)(unsigned short)s) << 16;
    return v.f;
}

// ---------------- fp32 -> bf16 convert ----------------
__global__ __launch_bounds__(256) void cvt_f32_bf16(const float* __restrict__ in,
                                                    short* __restrict__ out) {
    const int i = (blockIdx.x * 256 + threadIdx.x) * 4;
    const float4 v = *(const float4*)(in + i);
    short4v o;
    o[0] = (short)f2bf(v.x); o[1] = (short)f2bf(v.y);
    o[2] = (short)f2bf(v.z); o[3] = (short)f2bf(v.w);
    *(short4v*)(out + i) = o;
}

// ---------------- fp32 [R][C] -> bf16 [C][R] transpose+convert ----------------
__global__ __launch_bounds__(256) void transpose_cvt(const float* __restrict__ in,
                                                     short* __restrict__ out,
                                                     int R, int C) {
    __shared__ float tile[64 * 65];
    const int t = threadIdx.x;
    const int r0 = blockIdx.y * 64, c0 = blockIdx.x * 64;
    const int rl = t >> 4, cl4 = (t & 15) * 4;
#pragma unroll
    for (int rep = 0; rep < 4; rep++) {
        const int r = rep * 16 + rl;
        const float4 v = *(const float4*)(in + (long)(r0 + r) * C + c0 + cl4);
        tile[r * 65 + cl4 + 0] = v.x;
        tile[r * 65 + cl4 + 1] = v.y;
        tile[r * 65 + cl4 + 2] = v.z;
        tile[r * 65 + cl4 + 3] = v.w;
    }
    __syncthreads();
#pragma unroll
    for (int rep = 0; rep < 4; rep++) {
        const int cc = rep * 16 + rl;
        short4v o;
#pragma unroll
        for (int j = 0; j < 4; j++) o[j] = (short)f2bf(tile[(cl4 + j) * 65 + cc]);
        *(short4v*)(out + (long)(c0 + cc) * R + r0 + cl4) = o;
    }
}

// ---------------- NT GEMM: C = A[M][K](bf16,k-major) * Bt[N][K]^T ----------------
// OUTMODE: 0 = fp32 plain row-major [M][N]; 2 = bf16 head-major QKV[u=f>>8][m][d=f&255]
template<int N, int K, int OUTMODE>
__global__ __launch_bounds__(256) void gemm_nt(const short* __restrict__ A,
                                               const short* __restrict__ Bt,
                                               void* __restrict__ Cv) {
    __shared__ __align__(16) short Al[128 * 32];
    __shared__ __align__(16) short Bl[128 * 32];
    const int t = threadIdx.x;
    const int lane = t & 63, w = t >> 6;
    const int quad = lane >> 4, l16 = lane & 15;
    const int wr = w >> 1, wc = w & 1;
    const long m0 = (long)blockIdx.y * 128, n0 = (long)blockIdx.x * 128;

    const short* Ag0 = A + (m0 + (t >> 2)) * K + (t & 3) * 8;
    const short* Bg0 = Bt + (n0 + (t >> 2)) * K + (t & 3) * 8;

    f32x4 acc[4][4] = {};

    for (int k0 = 0; k0 < K; k0 += 32) {
        __syncthreads();
        GLOAD16(Ag0 + k0,            Al + t * 8);
        GLOAD16(Ag0 + 64 * K + k0,   Al + (t + 256) * 8);
        GLOAD16(Bg0 + k0,            Bl + t * 8);
        GLOAD16(Bg0 + 64 * K + k0,   Bl + (t + 256) * 8);
        __syncthreads();
        short8 af[4], bfr[4];
#pragma unroll
        for (int i = 0; i < 4; i++)
            af[i] = *(const short8*)(Al + (wr * 64 + i * 16 + l16) * 32 + quad * 8);
#pragma unroll
        for (int i = 0; i < 4; i++)
            bfr[i] = *(const short8*)(Bl + (wc * 64 + i * 16 + l16) * 32 + quad * 8);
#pragma unroll
        for (int mi = 0; mi < 4; mi++)
#pragma unroll
            for (int ni = 0; ni < 4; ni++)
                acc[mi][ni] = __builtin_amdgcn_mfma_f32_16x16x32_bf16(af[mi], bfr[ni], acc[mi][ni], 0, 0, 0);
    }

    const long crow = m0 + wr * 64 + quad * 4;
    const long ccol = n0 + wc * 64 + l16;
    if constexpr (OUTMODE == 0) {
        float* C = (float*)Cv;
#pragma unroll
        for (int mi = 0; mi < 4; mi++)
#pragma unroll
            for (int ni = 0; ni < 4; ni++)
#pragma unroll
                for (int r = 0; r < 4; r++)
                    C[(crow + mi * 16 + r) * N + ccol + ni * 16] = acc[mi][ni][r];
    } else {
        short* C = (short*)Cv;
#pragma unroll
        for (int mi = 0; mi < 4; mi++)
#pragma unroll
            for (int ni = 0; ni < 4; ni++)
#pragma unroll
                for (int r = 0; r < 4; r++) {
                    const long m = crow + mi * 16 + r;
                    const long f = ccol + ni * 16;
                    C[(f >> 8) * 1048576 + m * 256 + (f & 255)] = (short)f2bf(acc[mi][ni][r]);
                }
    }
}

// ---------------- RMS-norm + RoPE in-place; V -> Vt transpose ----------------
// QKV bf16 [32 units][4096 m=b*2048+s][256 d]. Units 0..15 = Q heads (scaled 1/16),
// 16..23 = K heads, 24..31 = V heads -> Vt[(u-24)*2+b][d][s].
__global__ __launch_bounds__(256) void prep_qkv(short* __restrict__ QKV,
                                                const float* __restrict__ cosp,
                                                const float* __restrict__ sinp,
                                                const float* __restrict__ qw,
                                                const float* __restrict__ kw,
                                                short* __restrict__ Vt) {
    const int t = threadIdx.x, w = t >> 6, lane = t & 63;
    const int d4 = lane * 4;
    const float sgn = (lane < 32) ? -1.0f : 1.0f;   // d<128 -> -x2, else +x1
#pragma unroll
    for (int i = 0; i < 4; i++) {
        const int g = blockIdx.x * 16 + w * 4 + i;  // 0..131071
        const int u = g >> 12, m = g & 4095;
        short* rowp = QKV + (long)g * 256;
        const short4v raw = *(const short4v*)(rowp + d4);
        if (u < 24) {
            float x[4];
#pragma unroll
            for (int j = 0; j < 4; j++) x[j] = bf2f(raw[j]);
            float ss = x[0]*x[0] + x[1]*x[1] + x[2]*x[2] + x[3]*x[3];
#pragma unroll
            for (int msk = 1; msk < 64; msk <<= 1) ss += __shfl_xor(ss, msk, 64);
            const float rinv = rsqrtf(ss * (1.0f / 256.0f) + 1e-6f);
            const float4 wv = *(const float4*)(((u < 16) ? qw : kw) + d4);
            const float wa[4] = {wv.x, wv.y, wv.z, wv.w};
            const float4 cv = *(const float4*)(cosp + (long)m * 256 + d4);
            const float4 sv = *(const float4*)(sinp + (long)m * 256 + d4);
            const float ca[4] = {cv.x, cv.y, cv.z, cv.w};
            const float sa[4] = {sv.x, sv.y, sv.z, sv.w};
            float n[4];
#pragma unroll
            for (int j = 0; j < 4; j++) n[j] = x[j] * rinv * (1.0f + wa[j]);
            const float scale = (u < 16) ? 0.0625f : 1.0f;
            short4v ov;
#pragma unroll
            for (int j = 0; j < 4; j++) {
                const float p = __shfl_xor(n[j], 32, 64);  // partner d +/- 128
                ov[j] = (short)f2bf((n[j] * ca[j] + sgn * p * sa[j]) * scale);
            }
            *(short4v*)(rowp + d4) = ov;
        } else {
            const int b = m >> 11, s = m & 2047;
            short* dst = Vt + ((long)((u - 24) * 2 + b) * 256 + d4) * 2048 + s;
#pragma unroll
            for (int j = 0; j < 4; j++) dst[(long)j * 2048] = raw[j];
        }
    }
}

// ---------------- flash attention ----------------
// grid (S/64, NH, B), 256 thr. QKV head-major: Q unit h, K unit 16+kh; Vt[(kh*2+b)][d][s].
__global__ __launch_bounds__(256) void attn(const short* __restrict__ QKV,
                                            const short* __restrict__ Vt,
                                            short* __restrict__ O) {
    __shared__ __align__(16) short Kl[64 * 256];   // [s][d], chunk-swizzled
    __shared__ __align__(16) short Vl[256 * 64];   // [d][s], chunk-swizzled
    __shared__ __align__(16) short Pl[64 * 72];    // padded rows (144B)
    __shared__ __align__(16) float Alp[64];
    __shared__ __align__(16) float Ll[64];

    const int t = threadIdx.x, w = t >> 6, lane = t & 63;
    const int quad = lane >> 4, l16 = lane & 15;
    const int q0 = blockIdx.x * 64, h = blockIdx.y, b = blockIdx.z;
    const int kh = h >> 1;
    const short* Qp = QKV + ((long)h * 4096 + b * 2048 + q0) * 256;
    const short* Kp = QKV + ((long)(16 + kh) * 4096 + b * 2048) * 256;
    const short* Vp = Vt + (long)(kh * 2 + b) * 256 * 2048;

    short8 qf[8];
#pragma unroll
    for (int ks = 0; ks < 8; ks++)
        qf[ks] = *(const short8*)(Qp + (w * 16 + l16) * 256 + ks * 32 + quad * 8);

    f32x4 acc[4][4] = {};
    float mi_[4], li_[4];
#pragma unroll
    for (int r = 0; r < 4; r++) { mi_[r] = -1e30f; li_[r] = 0.0f; }

    for (int kt = 0; kt < 32; kt++) {
        const int k0 = kt * 64;
        __syncthreads();
#pragma unroll
        for (int i = 0; i < 8; i++) {           // K tile: 64 rows x 256 d
            const int c = i * 256 + t;
            const int rK = c >> 5, dcK = (c & 31) ^ (rK & 31);
            GLOAD16(Kp + (long)(k0 + rK) * 256 + dcK * 8, Kl + c * 8);
        }
#pragma unroll
        for (int i = 0; i < 8; i++) {           // Vt tile: 256 d x 64 s
            const int c = i * 256 + t;
            const int dV = c >> 3, dcV = (c & 7) ^ (dV & 7);
            GLOAD16(Vp + (long)dV * 2048 + k0 + dcV * 8, Vl + c * 8);
        }
        __syncthreads();

        // ---- S = Q K^T (scale pre-folded into Q) ----
        f32x4 sc[4] = {};
#pragma unroll
        for (int ct = 0; ct < 4; ct++) {
            const int rowK = ct * 16 + l16;
#pragma unroll
            for (int ks = 0; ks < 8; ks++) {
                const int dc = (ks * 4 + quad) ^ (rowK & 31);
                const short8 kf = *(const short8*)(Kl + rowK * 256 + dc * 8);
                sc[ct] = __builtin_amdgcn_mfma_f32_16x16x32_bf16(qf[ks], kf, sc[ct], 0, 0, 0);
            }
        }

        // ---- online softmax (rows w*16+quad*4+r, cols ct*16+l16) ----
        float al[4];
#pragma unroll
        for (int r = 0; r < 4; r++) {
            float v = fmaxf(fmaxf(sc[0][r], sc[1][r]), fmaxf(sc[2][r], sc[3][r]));
            v = fmaxf(v, __shfl_xor(v, 1, 64));
            v = fmaxf(v, __shfl_xor(v, 2, 64));
            v = fmaxf(v, __shfl_xor(v, 4, 64));
            v = fmaxf(v, __shfl_xor(v, 8, 64));
            const float mn = fmaxf(mi_[r], v);
            al[r] = __expf(mi_[r] - mn);
            mi_[r] = mn;
        }
        float rs[4] = {0.0f, 0.0f, 0.0f, 0.0f};
#pragma unroll
        for (int ct = 0; ct < 4; ct++) {
#pragma unroll
            for (int r = 0; r < 4; r++) {
                const float p = __expf(sc[ct][r] - mi_[r]);
                rs[r] += p;
                Pl[(w * 16 + quad * 4 + r) * 72 + ct * 16 + l16] = (short)f2bf(p);
            }
        }
#pragma unroll
        for (int r = 0; r < 4; r++) {
            float v = rs[r];
            v += __shfl_xor(v, 1, 64);
            v += __shfl_xor(v, 2, 64);
            v += __shfl_xor(v, 4, 64);
            v += __shfl_xor(v, 8, 64);
            li_[r] = li_[r] * al[r] + v;
        }
        if (l16 == 0) {
#pragma unroll
            for (int r = 0; r < 4; r++) Alp[w * 16 + quad * 4 + r] = al[r];
        }
        __syncthreads();

        // ---- rescale O, then O += P V (wave w owns d strip [64w,64w+64)) ----
#pragma unroll
        for (int mi2 = 0; mi2 < 4; mi2++) {
            const float4 av = *(const float4*)(Alp + mi2 * 16 + quad * 4);
            const float aa[4] = {av.x, av.y, av.z, av.w};
#pragma unroll
            for (int ni = 0; ni < 4; ni++)
#pragma unroll
                for (int r = 0; r < 4; r++)
                    acc[mi2][ni][r] *= aa[r];
        }
#pragma unroll
        for (int k2 = 0; k2 < 2; k2++) {
            short8 pf[4];
#pragma unroll
            for (int mi2 = 0; mi2 < 4; mi2++)
                pf[mi2] = *(const short8*)(Pl + (mi2 * 16 + l16) * 72 + k2 * 32 + quad * 8);
#pragma unroll
            for (int ni = 0; ni < 4; ni++) {
                const int dV = w * 64 + ni * 16 + l16;
                const int dc = (k2 * 4 + quad) ^ (dV & 7);
                const short8 vf = *(const short8*)(Vl + dV * 64 + dc * 8);
#pragma unroll
                for (int mi2 = 0; mi2 < 4; mi2++)
                    acc[mi2][ni] = __builtin_amdgcn_mfma_f32_16x16x32_bf16(pf[mi2], vf, acc[mi2][ni], 0, 0, 0);
            }
        }
    }

    if (l16 == 0) {
#pragma unroll
        for (int r = 0; r < 4; r++) Ll[w * 16 + quad * 4 + r] = li_[r];
    }
    __syncthreads();

    short* Op = O + (long)(b * 2048 + q0) * 4096 + h * 256 + w * 64;
#pragma unroll
    for (int mi2 = 0; mi2 < 4; mi2++) {
        const float4 lv = *(const float4*)(Ll + mi2 * 16 + quad * 4);
        const float inv[4] = {1.0f / lv.x, 1.0f / lv.y, 1.0f / lv.z, 1.0f / lv.w};
#pragma unroll
        for (int ni = 0; ni < 4; ni++)
#pragma unroll
            for (int r = 0; r < 4; r++)
                Op[(long)(mi2 * 16 + quad * 4 + r) * 4096 + ni * 16 + l16] =
                    (short)f2bf(acc[mi2][ni][r] * inv[r]);
    }
}

// ---------------- launch ----------------
// Workspace: 117,440,512 bytes total.
//   poolA [0 .. 25.17M shorts): Xb [4096][2048] @0, Wqkv_t [8192][2048] @8.39M
//     overlays (after gemm1): Vt [16][256][2048] @0, Ob [4096][4096] @8.39M
//   QKV @25.17M shorts: [32][4096][256]  (overlay after attn: Wo_t [2048][4096])
extern "C" void kernel_launch(void* const* d_in, const int* in_sizes, int n_in,
                              void* d_out, int out_size, void* d_ws, size_t ws_size,
                              hipStream_t stream) {
    const float* hs   = (const float*)d_in[0];
    const float* cosp = (const float*)d_in[1];
    const float* sinp = (const float*)d_in[2];
    const float* wqkv = (const float*)d_in[3];
    const float* wo   = (const float*)d_in[4];
    const float* qnw  = (const float*)d_in[5];
    const float* knw  = (const float*)d_in[6];
    float* out = (float*)d_out;

    short* poolA  = (short*)d_ws;
    short* Xb     = poolA;                                  // [4096][2048]
    short* Wqkv_t = poolA + (size_t)4096 * 2048;            // [8192][2048]
    short* QKV    = poolA + (size_t)4096 * 2048 + (size_t)8192 * 2048; // [32][4096][256]
    short* Vt     = poolA;                                  // [16][256][2048] (over Xb)
    short* Ob     = poolA + (size_t)16 * 256 * 2048;        // [4096][4096] (over Wqkv_t)
    short* Wo_t   = QKV;                                    // [2048][4096] (over QKV, post-attn)

    cvt_f32_bf16<<<8192, 256, 0, stream>>>(hs, Xb);
    transpose_cvt<<<dim3(128, 32), 256, 0, stream>>>(wqkv, Wqkv_t, 2048, 8192);
    gemm_nt<8192, 2048, 2><<<dim3(64, 32), 256, 0, stream>>>(Xb, Wqkv_t, (void*)QKV);
    prep_qkv<<<8192, 256, 0, stream>>>(QKV, cosp, sinp, qnw, knw, Vt);
    attn<<<dim3(32, 16, 2), 256, 0, stream>>>(QKV, Vt, Ob);
    transpose_cvt<<<dim3(32, 64), 256, 0, stream>>>(wo, Wo_t, 4096, 2048);
    gemm_nt<2048, 4096, 0><<<dim3(16, 32), 256, 0, stream>>>(Ob, Wo_t, (void*)out);
}